// Round 2
// baseline (114.370 us; speedup 1.0000x reference)
//
#include <hip/hip_runtime.h>
#include <stdint.h>

// ---------------------------------------------------------------------------
// NT-Xent loss, B=8 S=512 D=128  ->  N=4096, 2N=8192 rows, K=128.
// loss = mean_i( -pos_i + log(sum_{j!=i} exp(sim_ij)) ),  sim = z_n z_n^T / T
//
// v3: symmetric upper-triangle 128x128 tiles (2080 blocks) as v2, but:
//  * 4 waves/block (256 thr), each wave 32 rows x 128 cols -> 2x TLP/CU,
//    halved per-thread staging (64 B), halved afrag VGPRs.
//  * NO global atomics (v2's ~530K device-scope atomics all went to HBM:
//    WRITE_SIZE 39.5MB = 64B x 618K lines). Blocks store 128 row-partials +
//    128 col-partials to scratch[blk][256]; ntx_redu gathers the 64
//    contributions per row (closed-form triangular indexing, coalesced L2
//    reads) and takes the log; ntx_final adds the pos terms.
//
//  k1: normalize rows (fp32), pos_half in fp32, store z_n * SCALE as bf16
//      where SCALE^2 = log2(e)/T, so MFMA acc = sim*log2e and
//      exp(sim) == exp2(acc) == one v_exp_f32.
//  k2: symmetric Gram + exp row/col partial sums -> scratch.
//  k3: ntx_redu: rowsum_i = sum of 64 block partials; lpart[I] = sum log.
//  k4: ntx_final: loss = (sum lpart - 2*sum pos_half) / 8192.
// No max-subtraction needed: logits in [-14.3,14.3], sums < 1.3e10 (fp32-safe).
// ---------------------------------------------------------------------------

#define TOTAL   8192
#define NHALF   4096
#define DK      128
#define TEMP_INV 14.285714285714286f
#define SCALE    4.539816f      // sqrt(log2(e)/0.07); SCALE^2 = 20.609929

#define TILE    128                       // square tile edge
#define TILES   (TOTAL / TILE)            // 64
#define NBLK    (TILES * (TILES + 1) / 2) // 2080 super-diagonal tiles
#define BN      64                        // cols staged per LDS stage
#define NSTAGE  (TILE / BN)               // 2

typedef short  bf16x8  __attribute__((ext_vector_type(8)));
typedef float  floatx4 __attribute__((ext_vector_type(4)));

#if __has_builtin(__builtin_amdgcn_exp2f)
#define EXP2(x) __builtin_amdgcn_exp2f(x)
#else
#define EXP2(x) exp2f(x)
#endif

__device__ __forceinline__ uint32_t f2bf(float f) {
  uint32_t u = __float_as_uint(f);
  return (u + 0x7fffu + ((u >> 16) & 1u)) >> 16;   // RNE; inputs finite
}
__device__ __forceinline__ uint32_t pack2bf(float lo, float hi) {
  return f2bf(lo) | (f2bf(hi) << 16);
}

// --------------------------- kernel 1: normalize ---------------------------
// grid 1024 x 256. Each wave handles one i (both z_i and z_j rows).
__global__ __launch_bounds__(256) void ntx_norm(
    const float* __restrict__ zi, const float* __restrict__ zj,
    uint32_t* __restrict__ zn,   // packed 2xbf16, [TOTAL][64]
    float* __restrict__ pos)     // [NHALF]
{
  const int t = threadIdx.x;
  const int wave = t >> 6, lane = t & 63;
  const int i = blockIdx.x * 4 + wave;

  const float2 vi = *(const float2*)(zi + (size_t)i * DK + lane * 2);
  const float2 vj = *(const float2*)(zj + (size_t)i * DK + lane * 2);
  float ssi = vi.x * vi.x + vi.y * vi.y;
  float ssj = vj.x * vj.x + vj.y * vj.y;
  float dij = vi.x * vj.x + vi.y * vj.y;
#pragma unroll
  for (int m = 1; m <= 32; m <<= 1) {
    ssi += __shfl_xor(ssi, m, 64);
    ssj += __shfl_xor(ssj, m, 64);
    dij += __shfl_xor(dij, m, 64);
  }
  const float invi = 1.0f / fmaxf(sqrtf(ssi), 1e-12f);
  const float invj = 1.0f / fmaxf(sqrtf(ssj), 1e-12f);

  zn[(size_t)i * 64 + lane] =
      pack2bf(vi.x * invi * SCALE, vi.y * invi * SCALE);
  zn[(size_t)(i + NHALF) * 64 + lane] =
      pack2bf(vj.x * invj * SCALE, vj.y * invj * SCALE);
  if (lane == 0) pos[i] = dij * invi * invj * TEMP_INV;
}

// ---------------- kernel 2: symmetric Gram + exp partial sums --------------
// grid NBLK x 256. Linear block id -> upper-triangular tile (I, J), J >= I.
// 4 waves, wave w owns rows [i0+32w, i0+32w+32) x all 128 cols.
__global__ __launch_bounds__(256, 6) void ntx_gemm(
    const uint16_t* __restrict__ z,   // [TOTAL][DK] bf16 (scaled)
    float* __restrict__ scratch)      // [NBLK][256]: 128 row + 128 col parts
{
  __shared__ uint4 lb4[BN * 17];      // 64 rows x (256B data + 16B pad)
  __shared__ float colacc[4][TILE];   // per-wave column partial sums

  // map linear block id -> (I, J) with J >= I  (row-major upper triangle)
  int I = 0, rem = (int)blockIdx.x, span = TILES;
  while (rem >= span) { rem -= span; --span; ++I; }
  const int J = I + rem;
  const bool isdiag = (I == J);

  const int t = threadIdx.x;
  const int wave = t >> 6, lane = t & 63;
  const int q = lane >> 4, c = lane & 15;
  const int i0 = I * TILE;
  const int j0 = J * TILE;
  const int rowbase = i0 + wave * 32;

  // A fragments: 2 strips x 4 k-steps, in registers for the whole block.
  // A[m=c][k=q*8+j] -> z[rowbase+s*16+c][kk*32+q*8 .. +8]
  bf16x8 afrag[2][4];
#pragma unroll
  for (int s = 0; s < 2; ++s) {
    const uint16_t* ap = z + (size_t)(rowbase + s * 16 + c) * DK + q * 8;
#pragma unroll
    for (int kk = 0; kk < 4; ++kk)
      afrag[s][kk] = *(const bf16x8*)(ap + kk * 32);
  }

  float runsum[2][4];
#pragma unroll
  for (int s = 0; s < 2; ++s)
#pragma unroll
    for (int r = 0; r < 4; ++r) runsum[s][r] = 0.0f;

  const int ch = t & 15;     // 16B chunk within a row
  const int r0 = t >> 4;     // staging row 0..15

  for (int st = 0; st < NSTAGE; ++st) {
    const int jst = j0 + st * BN;
    __syncthreads();   // previous stage's reads done before overwrite
#pragma unroll
    for (int p = 0; p < 4; ++p) {
      const int r = r0 + p * 16;
      uint4 v = *(const uint4*)(z + (size_t)(jst + r) * DK + ch * 8);
      lb4[r * 17 + ch] = v;
    }
    __syncthreads();

#pragma unroll
    for (int jt = 0; jt < BN / 16; ++jt) {
      // B[k=q*8+j][n=c] -> lds row (jt*16+c), bytes kk*64 + q*16
      bf16x8 bfrag[4];
#pragma unroll
      for (int kk = 0; kk < 4; ++kk)
        bfrag[kk] = *(const bf16x8*)&lb4[(jt * 16 + c) * 17 + kk * 4 + q];
      const int jc = jst + jt * 16;    // col = jc + c

      float colv = 0.0f;
#pragma unroll
      for (int s = 0; s < 2; ++s) {
        floatx4 acc = {0.0f, 0.0f, 0.0f, 0.0f};
#pragma unroll
        for (int kk = 0; kk < 4; ++kk)
          acc = __builtin_amdgcn_mfma_f32_16x16x32_bf16(afrag[s][kk],
                                                        bfrag[kk], acc,
                                                        0, 0, 0);
        const int rb = rowbase + s * 16;   // row = rb + q*4 + r
        if (!isdiag) {                     // off-diagonal block: row+col sums
#pragma unroll
          for (int r = 0; r < 4; ++r) {
            float e = EXP2(acc[r]);
            runsum[s][r] += e;
            colv += e;
          }
        } else if (jc == rb) {             // diagonal tile (wave-uniform)
#pragma unroll
          for (int r = 0; r < 4; ++r) {
            float e = EXP2(acc[r]);
            runsum[s][r] += (q * 4 + r == c) ? 0.0f : e;
          }
        } else {                           // diag block, off-diag tile
#pragma unroll
          for (int r = 0; r < 4; ++r) runsum[s][r] += EXP2(acc[r]);
        }
      }

      if (!isdiag) {
        // column sums over this wave's 32 rows: combine the 4 q-groups
        colv += __shfl_xor(colv, 16, 64);
        colv += __shfl_xor(colv, 32, 64);
        if (lane < 16)
          colacc[wave][st * BN + jt * 16 + lane] = colv;  // each col once
      }
    }
  }

  // row partials: reduce across the 16 c-lanes (same q), store per block
  float* sblk = scratch + (size_t)blockIdx.x * 256;
#pragma unroll
  for (int s = 0; s < 2; ++s)
#pragma unroll
    for (int r = 0; r < 4; ++r) {
      float v = runsum[s][r];
      v += __shfl_xor(v, 1, 64);
      v += __shfl_xor(v, 2, 64);
      v += __shfl_xor(v, 4, 64);
      v += __shfl_xor(v, 8, 64);
      runsum[s][r] = v;
    }
  if (c == 0) {
#pragma unroll
    for (int s = 0; s < 2; ++s)
#pragma unroll
      for (int r = 0; r < 4; ++r)
        sblk[wave * 32 + s * 16 + q * 4 + r] = runsum[s][r];
  }

  // column partials (off-diagonal blocks only)
  __syncthreads();
  if (!isdiag && t < TILE)
    sblk[128 + t] = colacc[0][t] + colacc[1][t] + colacc[2][t] + colacc[3][t];
}

// ------------------- kernel 3: gather partials, log-reduce -----------------
// grid 64 x 128. Block I handles rows [128I, 128I+128); thread o = one row.
// rowsum_i = sum_{J=I..63} scratch[id(I,J)][o] + sum_{I'<I} scratch[id(I',I)][128+o]
// id(I,J) = I*64 - I(I-1)/2 + (J-I);  id(I'+1,I) - id(I',I) = 63 - I'.
__global__ __launch_bounds__(128) void ntx_redu(
    const float* __restrict__ scratch, float* __restrict__ lpart)
{
  const int I = (int)blockIdx.x;
  const int o = (int)threadIdx.x;

  float S0 = 0.0f, S1 = 0.0f;
  int id = I * TILES - (I * (I - 1)) / 2;        // id(I, I)
#pragma unroll 4
  for (int J = I; J < TILES; ++J, ++id)
    S0 += scratch[(size_t)id * 256 + o];
  int idc = I;                                    // id(0, I)
#pragma unroll 4
  for (int Ip = 0; Ip < I; ++Ip) {
    S1 += scratch[(size_t)idc * 256 + 128 + o];
    idc += TILES - 1 - Ip;
  }

  float v = __logf(S0 + S1);
#pragma unroll
  for (int m = 1; m <= 32; m <<= 1) v += __shfl_xor(v, m, 64);
  __shared__ float red[2];
  if ((o & 63) == 0) red[o >> 6] = v;
  __syncthreads();
  if (o == 0) lpart[I] = red[0] + red[1];
}

// --------------------------- kernel 4: finalize ----------------------------
__global__ __launch_bounds__(256) void ntx_final(
    const float* __restrict__ lpart, const float* __restrict__ pos,
    float* __restrict__ out)
{
  const int t = threadIdx.x;
  float acc = (t < TILES) ? lpart[t] : 0.0f;
  for (int r = t; r < NHALF; r += 256) acc -= 2.0f * pos[r];
#pragma unroll
  for (int m = 1; m <= 32; m <<= 1) acc += __shfl_xor(acc, m, 64);
  __shared__ float red[4];
  if ((t & 63) == 0) red[t >> 6] = acc;
  __syncthreads();
  if (t == 0) out[0] = (red[0] + red[1] + red[2] + red[3]) / (float)TOTAL;
}

// ---------------------------------------------------------------------------
extern "C" void kernel_launch(void* const* d_in, const int* in_sizes, int n_in,
                              void* d_out, int out_size, void* d_ws,
                              size_t ws_size, hipStream_t stream) {
  const float* zi = (const float*)d_in[0];
  const float* zj = (const float*)d_in[1];
  float* out = (float*)d_out;

  char* ws = (char*)d_ws;
  uint16_t* zn      = (uint16_t*)ws;                          // 2 MiB bf16
  float*    scratch = (float*)(ws + (size_t)TOTAL * DK * 2);  // 2.13 MB
  float*    lpart   = (float*)(ws + (size_t)TOTAL * DK * 2
                               + (size_t)NBLK * 256 * 4);     // 256 B
  float*    pos     = (float*)(ws + (size_t)TOTAL * DK * 2
                               + (size_t)NBLK * 256 * 4 + 256);  // 16 KB

  ntx_norm<<<dim3(NHALF / 4), dim3(256), 0, stream>>>(zi, zj, (uint32_t*)zn,
                                                      pos);
  ntx_gemm<<<dim3(NBLK), dim3(256), 0, stream>>>(zn, scratch);
  ntx_redu<<<dim3(TILES), dim3(128), 0, stream>>>(scratch, lpart);
  ntx_final<<<dim3(1), dim3(256), 0, stream>>>(lpart, pos, out);
}

// Round 3
// 113.589 us; speedup vs baseline: 1.0069x; 1.0069x over previous
//
#include <hip/hip_runtime.h>
#include <stdint.h>

// ---------------------------------------------------------------------------
// NT-Xent loss, B=8 S=512 D=128  ->  N=4096, 2N=8192 rows, K=128.
// loss = mean_i( -pos_i + log(sum_{j!=i} exp(sim_ij)) ),  sim = z_n z_n^T / T
//
// v4: symmetric upper-triangle 128x128 tiles (2080 blocks), 4 waves/block,
// each wave 32 rows x 128 cols.  NO LDS staging for B: for
// mfma_f32_16x16x32_bf16 the A-fragment A[m=c][k=q*8+j] and B-fragment
// B[k=q*8+j][n=c] have the IDENTICAL per-lane address pattern into row-major
// z, so B-frags are loaded directly from global (z is 2 MB -> L2-resident;
// 4x redundant reads ~= 333 MB of L2 traffic ~= 10 us at 34.5 TB/s, fully
// overlapped).  This removes all mid-loop barriers + staging instructions
// that made v2/v3 stall-bound (>90% stall vs issue floor).  LDS: 2 KB colacc
// only; one __syncthreads at the epilogue.
//
//  k1: normalize rows (fp32), pos_half in fp32, store z_n * SCALE as bf16
//      where SCALE^2 = log2(e)/T, so MFMA acc = sim*log2e and
//      exp(sim) == exp2(acc) == one v_exp_f32.
//  k2: symmetric Gram + exp row/col partial sums -> scratch[blk][256]
//      (128 row partials + 128 col partials; no global atomics).
//  k3: ntx_redu: rowsum_i = sum of 64 block partials (closed-form triangular
//      indexing, coalesced); lpart[I] = sum_i log(rowsum_i).
//  k4: ntx_final: loss = (sum lpart - 2*sum pos_half) / 8192.
// No max-subtraction needed: logits in [-14.3,14.3], sums < 1.3e10 (fp32-safe).
// ---------------------------------------------------------------------------

#define TOTAL   8192
#define NHALF   4096
#define DK      128
#define TEMP_INV 14.285714285714286f
#define SCALE    4.539816f      // sqrt(log2(e)/0.07); SCALE^2 = 20.609929

#define TILE    128                       // square tile edge
#define TILES   (TOTAL / TILE)            // 64
#define NBLK    (TILES * (TILES + 1) / 2) // 2080 super-diagonal tiles

typedef short  bf16x8  __attribute__((ext_vector_type(8)));
typedef float  floatx4 __attribute__((ext_vector_type(4)));

#if __has_builtin(__builtin_amdgcn_exp2f)
#define EXP2(x) __builtin_amdgcn_exp2f(x)
#else
#define EXP2(x) exp2f(x)
#endif

__device__ __forceinline__ uint32_t f2bf(float f) {
  uint32_t u = __float_as_uint(f);
  return (u + 0x7fffu + ((u >> 16) & 1u)) >> 16;   // RNE; inputs finite
}
__device__ __forceinline__ uint32_t pack2bf(float lo, float hi) {
  return f2bf(lo) | (f2bf(hi) << 16);
}

// --------------------------- kernel 1: normalize ---------------------------
// grid 1024 x 256. Each wave handles one i (both z_i and z_j rows).
__global__ __launch_bounds__(256) void ntx_norm(
    const float* __restrict__ zi, const float* __restrict__ zj,
    uint32_t* __restrict__ zn,   // packed 2xbf16, [TOTAL][64]
    float* __restrict__ pos)     // [NHALF]
{
  const int t = threadIdx.x;
  const int wave = t >> 6, lane = t & 63;
  const int i = blockIdx.x * 4 + wave;

  const float2 vi = *(const float2*)(zi + (size_t)i * DK + lane * 2);
  const float2 vj = *(const float2*)(zj + (size_t)i * DK + lane * 2);
  float ssi = vi.x * vi.x + vi.y * vi.y;
  float ssj = vj.x * vj.x + vj.y * vj.y;
  float dij = vi.x * vj.x + vi.y * vj.y;
#pragma unroll
  for (int m = 1; m <= 32; m <<= 1) {
    ssi += __shfl_xor(ssi, m, 64);
    ssj += __shfl_xor(ssj, m, 64);
    dij += __shfl_xor(dij, m, 64);
  }
  const float invi = 1.0f / fmaxf(sqrtf(ssi), 1e-12f);
  const float invj = 1.0f / fmaxf(sqrtf(ssj), 1e-12f);

  zn[(size_t)i * 64 + lane] =
      pack2bf(vi.x * invi * SCALE, vi.y * invi * SCALE);
  zn[(size_t)(i + NHALF) * 64 + lane] =
      pack2bf(vj.x * invj * SCALE, vj.y * invj * SCALE);
  if (lane == 0) pos[i] = dij * invi * invj * TEMP_INV;
}

// ---------------- kernel 2: symmetric Gram + exp partial sums --------------
// grid NBLK x 256. Linear block id -> upper-triangular tile (I, J), J >= I.
// 4 waves, wave w owns rows [i0+32w, i0+32w+32) x all 128 cols.
// A and B fragments both loaded directly from global (identical lane layout).
__global__ __launch_bounds__(256, 4) void ntx_gemm(
    const uint16_t* __restrict__ z,   // [TOTAL][DK] bf16 (scaled)
    float* __restrict__ scratch)      // [NBLK][256]: 128 row + 128 col parts
{
  __shared__ float colacc[4][TILE];   // per-wave column partial sums (2 KB)

  // map linear block id -> (I, J) with J >= I  (row-major upper triangle)
  int I = 0, rem = (int)blockIdx.x, span = TILES;
  while (rem >= span) { rem -= span; --span; ++I; }
  const int J = I + rem;
  const bool isdiag = (I == J);

  const int t = threadIdx.x;
  const int wave = t >> 6, lane = t & 63;
  const int q = lane >> 4, c = lane & 15;
  const int i0 = I * TILE;
  const int j0 = J * TILE;
  const int rowbase = i0 + wave * 32;

  // A fragments: 2 strips x 4 k-steps, in registers for the whole block.
  // A[m=c][k=q*8+j] -> z[rowbase+s*16+c][kk*32+q*8 .. +8]
  bf16x8 afrag[2][4];
#pragma unroll
  for (int s = 0; s < 2; ++s) {
    const uint16_t* ap = z + (size_t)(rowbase + s * 16 + c) * DK + q * 8;
#pragma unroll
    for (int kk = 0; kk < 4; ++kk)
      afrag[s][kk] = *(const bf16x8*)(ap + kk * 32);
  }

  float runsum[2][4];
#pragma unroll
  for (int s = 0; s < 2; ++s)
#pragma unroll
    for (int r = 0; r < 4; ++r) runsum[s][r] = 0.0f;

#pragma unroll 2
  for (int jt = 0; jt < TILE / 16; ++jt) {
    const int jc = j0 + jt * 16;       // col = jc + c
    // B[k=q*8+j][n=c] -> z[jc+c][kk*32+q*8 .. +8]  (same layout as A)
    bf16x8 bfrag[4];
    const uint16_t* bp = z + (size_t)(jc + c) * DK + q * 8;
#pragma unroll
    for (int kk = 0; kk < 4; ++kk)
      bfrag[kk] = *(const bf16x8*)(bp + kk * 32);

    float colv = 0.0f;
#pragma unroll
    for (int s = 0; s < 2; ++s) {
      floatx4 acc = {0.0f, 0.0f, 0.0f, 0.0f};
#pragma unroll
      for (int kk = 0; kk < 4; ++kk)
        acc = __builtin_amdgcn_mfma_f32_16x16x32_bf16(afrag[s][kk],
                                                      bfrag[kk], acc,
                                                      0, 0, 0);
      const int rb = rowbase + s * 16;   // row = rb + q*4 + r
      if (!isdiag) {                     // off-diagonal block: row+col sums
#pragma unroll
        for (int r = 0; r < 4; ++r) {
          float e = EXP2(acc[r]);
          runsum[s][r] += e;
          colv += e;
        }
      } else if (jc == rb) {             // diagonal tile (wave-uniform)
#pragma unroll
        for (int r = 0; r < 4; ++r) {
          float e = EXP2(acc[r]);
          runsum[s][r] += (q * 4 + r == c) ? 0.0f : e;
        }
      } else {                           // diag block, off-diag tile
#pragma unroll
        for (int r = 0; r < 4; ++r) runsum[s][r] += EXP2(acc[r]);
      }
    }

    if (!isdiag) {
      // column sums over this wave's 32 rows: combine the 4 q-groups
      colv += __shfl_xor(colv, 16, 64);
      colv += __shfl_xor(colv, 32, 64);
      if (lane < 16)
        colacc[wave][jt * 16 + lane] = colv;   // each col exactly once
    }
  }

  // row partials: reduce across the 16 c-lanes (same q), store per block
  float* sblk = scratch + (size_t)blockIdx.x * 256;
#pragma unroll
  for (int s = 0; s < 2; ++s)
#pragma unroll
    for (int r = 0; r < 4; ++r) {
      float v = runsum[s][r];
      v += __shfl_xor(v, 1, 64);
      v += __shfl_xor(v, 2, 64);
      v += __shfl_xor(v, 4, 64);
      v += __shfl_xor(v, 8, 64);
      runsum[s][r] = v;
    }
  if (c == 0) {
#pragma unroll
    for (int s = 0; s < 2; ++s)
#pragma unroll
      for (int r = 0; r < 4; ++r)
        sblk[wave * 32 + s * 16 + q * 4 + r] = runsum[s][r];
  }

  // column partials (off-diagonal blocks only)
  __syncthreads();
  if (!isdiag && t < TILE)
    sblk[128 + t] = colacc[0][t] + colacc[1][t] + colacc[2][t] + colacc[3][t];
}

// ------------------- kernel 3: gather partials, log-reduce -----------------
// grid 64 x 128. Block I handles rows [128I, 128I+128); thread o = one row.
// rowsum_i = sum_{J=I..63} scratch[id(I,J)][o] + sum_{I'<I} scratch[id(I',I)][128+o]
// id(I,J) = I*64 - I(I-1)/2 + (J-I);  id(I'+1,I) - id(I',I) = 63 - I'.
__global__ __launch_bounds__(128) void ntx_redu(
    const float* __restrict__ scratch, float* __restrict__ lpart)
{
  const int I = (int)blockIdx.x;
  const int o = (int)threadIdx.x;

  float S0 = 0.0f, S1 = 0.0f;
  int id = I * TILES - (I * (I - 1)) / 2;        // id(I, I)
#pragma unroll 8
  for (int J = I; J < TILES; ++J, ++id)
    S0 += scratch[(size_t)id * 256 + o];
  int idc = I;                                    // id(0, I)
#pragma unroll 8
  for (int Ip = 0; Ip < I; ++Ip) {
    S1 += scratch[(size_t)idc * 256 + 128 + o];
    idc += TILES - 1 - Ip;
  }

  float v = __logf(S0 + S1);
#pragma unroll
  for (int m = 1; m <= 32; m <<= 1) v += __shfl_xor(v, m, 64);
  __shared__ float red[2];
  if ((o & 63) == 0) red[o >> 6] = v;
  __syncthreads();
  if (o == 0) lpart[I] = red[0] + red[1];
}

// --------------------------- kernel 4: finalize ----------------------------
__global__ __launch_bounds__(256) void ntx_final(
    const float* __restrict__ lpart, const float* __restrict__ pos,
    float* __restrict__ out)
{
  const int t = threadIdx.x;
  float acc = (t < TILES) ? lpart[t] : 0.0f;
  for (int r = t; r < NHALF; r += 256) acc -= 2.0f * pos[r];
#pragma unroll
  for (int m = 1; m <= 32; m <<= 1) acc += __shfl_xor(acc, m, 64);
  __shared__ float red[4];
  if ((t & 63) == 0) red[t >> 6] = acc;
  __syncthreads();
  if (t == 0) out[0] = (red[0] + red[1] + red[2] + red[3]) / (float)TOTAL;
}

// ---------------------------------------------------------------------------
extern "C" void kernel_launch(void* const* d_in, const int* in_sizes, int n_in,
                              void* d_out, int out_size, void* d_ws,
                              size_t ws_size, hipStream_t stream) {
  const float* zi = (const float*)d_in[0];
  const float* zj = (const float*)d_in[1];
  float* out = (float*)d_out;

  char* ws = (char*)d_ws;
  uint16_t* zn      = (uint16_t*)ws;                          // 2 MiB bf16
  float*    scratch = (float*)(ws + (size_t)TOTAL * DK * 2);  // 2.13 MB
  float*    lpart   = (float*)(ws + (size_t)TOTAL * DK * 2
                               + (size_t)NBLK * 256 * 4);     // 256 B
  float*    pos     = (float*)(ws + (size_t)TOTAL * DK * 2
                               + (size_t)NBLK * 256 * 4 + 256);  // 16 KB

  ntx_norm<<<dim3(NHALF / 4), dim3(256), 0, stream>>>(zi, zj, (uint32_t*)zn,
                                                      pos);
  ntx_gemm<<<dim3(NBLK), dim3(256), 0, stream>>>(zn, scratch);
  ntx_redu<<<dim3(TILES), dim3(128), 0, stream>>>(scratch, lpart);
  ntx_final<<<dim3(1), dim3(256), 0, stream>>>(lpart, pos, out);
}

// Round 4
// 105.806 us; speedup vs baseline: 1.0809x; 1.0736x over previous
//
#include <hip/hip_runtime.h>
#include <stdint.h>

// ---------------------------------------------------------------------------
// NT-Xent loss, B=8 S=512 D=128  ->  N=4096, 2N=8192 rows, K=128.
// loss = mean_i( -pos_i + log(sum_{j!=i} exp(sim_ij)) ),  sim = z_n z_n^T / T
//
// v5: symmetric upper-triangle 128x128 tiles (2080 blocks), 4 waves/block,
// each wave owns a 64x64 QUADRANT (w>>1 = row half, w&1 = col half).
// All A-fragments (4 strips) AND all B-fragments (4 col-tiles) are loaded
// upfront: 32 independent b128 global loads in flight per wave (z is 2 MB,
// L2-resident), then 64 MFMA + 64 exp2 run purely from registers.  This
// replaces v4's 8 serial (load -> vmcnt -> compute) iterations -- whose
// exposed L2 latency made the kernel 90%-stall (MfmaUtil 6.6%, VALUBusy 14%)
// -- with ONE exposed latency per wave.  B traffic also halves (each col
// read by 2 waves, not 4).  Row/col partials combined via 2 KB LDS.
//
//  k1: normalize rows (fp32), pos_half in fp32, store z_n * SCALE as bf16
//      where SCALE^2 = log2(e)/T, so MFMA acc = sim*log2e and
//      exp(sim) == exp2(acc) == one v_exp_f32.
//  k2: symmetric Gram + exp row/col partial sums -> scratch[blk][256]
//      (128 row partials + 128 col partials; no global atomics).
//  k3: ntx_redu: rowsum_i = sum of 64 block partials (closed-form triangular
//      indexing; the two gather loops split across 256 threads);
//      lpart[I] = sum_i log(rowsum_i).
//  k4: ntx_final: loss = (sum lpart - 2*sum pos_half) / 8192.
// No max-subtraction needed: logits in [-14.3,14.3], sums < 1.3e10 (fp32-safe).
// ---------------------------------------------------------------------------

#define TOTAL   8192
#define NHALF   4096
#define DK      128
#define TEMP_INV 14.285714285714286f
#define SCALE    4.539816f      // sqrt(log2(e)/0.07); SCALE^2 = 20.609929

#define TILE    128                       // square tile edge
#define TILES   (TOTAL / TILE)            // 64
#define NBLK    (TILES * (TILES + 1) / 2) // 2080 super-diagonal tiles

typedef short  bf16x8  __attribute__((ext_vector_type(8)));
typedef float  floatx4 __attribute__((ext_vector_type(4)));

#if __has_builtin(__builtin_amdgcn_exp2f)
#define EXP2(x) __builtin_amdgcn_exp2f(x)
#else
#define EXP2(x) exp2f(x)
#endif

__device__ __forceinline__ uint32_t f2bf(float f) {
  uint32_t u = __float_as_uint(f);
  return (u + 0x7fffu + ((u >> 16) & 1u)) >> 16;   // RNE; inputs finite
}
__device__ __forceinline__ uint32_t pack2bf(float lo, float hi) {
  return f2bf(lo) | (f2bf(hi) << 16);
}

// --------------------------- kernel 1: normalize ---------------------------
// grid 1024 x 256. Each wave handles one i (both z_i and z_j rows).
__global__ __launch_bounds__(256) void ntx_norm(
    const float* __restrict__ zi, const float* __restrict__ zj,
    uint32_t* __restrict__ zn,   // packed 2xbf16, [TOTAL][64]
    float* __restrict__ pos)     // [NHALF]
{
  const int t = threadIdx.x;
  const int wave = t >> 6, lane = t & 63;
  const int i = blockIdx.x * 4 + wave;

  const float2 vi = *(const float2*)(zi + (size_t)i * DK + lane * 2);
  const float2 vj = *(const float2*)(zj + (size_t)i * DK + lane * 2);
  float ssi = vi.x * vi.x + vi.y * vi.y;
  float ssj = vj.x * vj.x + vj.y * vj.y;
  float dij = vi.x * vj.x + vi.y * vj.y;
#pragma unroll
  for (int m = 1; m <= 32; m <<= 1) {
    ssi += __shfl_xor(ssi, m, 64);
    ssj += __shfl_xor(ssj, m, 64);
    dij += __shfl_xor(dij, m, 64);
  }
  const float invi = 1.0f / fmaxf(sqrtf(ssi), 1e-12f);
  const float invj = 1.0f / fmaxf(sqrtf(ssj), 1e-12f);

  zn[(size_t)i * 64 + lane] =
      pack2bf(vi.x * invi * SCALE, vi.y * invi * SCALE);
  zn[(size_t)(i + NHALF) * 64 + lane] =
      pack2bf(vj.x * invj * SCALE, vj.y * invj * SCALE);
  if (lane == 0) pos[i] = dij * invi * invj * TEMP_INV;
}

// ---------------- kernel 2: symmetric Gram + exp partial sums --------------
// grid NBLK x 256. Linear block id -> upper-triangular tile (I, J), J >= I.
// Wave w owns the 64x64 quadrant (rowhalf = w>>1, colhalf = w&1).
// A and B fragments both loaded directly from global (identical lane layout:
// frag[k=q*8+j][m-or-n=c] -> z[base+c][kk*32+q*8 .. +8]).
__global__ __launch_bounds__(256) void ntx_gemm(
    const uint16_t* __restrict__ z,   // [TOTAL][DK] bf16 (scaled)
    float* __restrict__ scratch)      // [NBLK][256]: 128 row + 128 col parts
{
  __shared__ float rowacc[4][64];     // per-wave row partial sums
  __shared__ float colacc[4][64];     // per-wave col partial sums

  // map linear block id -> (I, J) with J >= I  (row-major upper triangle)
  int I = 0, rem = (int)blockIdx.x, span = TILES;
  while (rem >= span) { rem -= span; --span; ++I; }
  const int J = I + rem;
  const bool isdiag = (I == J);

  const int t = threadIdx.x;
  const int w = t >> 6, lane = t & 63;
  const int q = lane >> 4, c = lane & 15;
  const int rowbase = I * TILE + (w >> 1) * 64;
  const int colbase = J * TILE + (w & 1) * 64;

  // 32 independent b128 loads, all issued before first use (max MLP).
  bf16x8 afrag[4][4];   // [strip s][kk]   rows rowbase+s*16+c
  bf16x8 bfrag[4][4];   // [coltile jt][kk] cols colbase+jt*16+c
#pragma unroll
  for (int s = 0; s < 4; ++s) {
    const uint16_t* ap = z + (size_t)(rowbase + s * 16 + c) * DK + q * 8;
    const uint16_t* bp = z + (size_t)(colbase + s * 16 + c) * DK + q * 8;
#pragma unroll
    for (int kk = 0; kk < 4; ++kk) {
      afrag[s][kk] = *(const bf16x8*)(ap + kk * 32);
      bfrag[s][kk] = *(const bf16x8*)(bp + kk * 32);
    }
  }

  float runsum[4][4];
#pragma unroll
  for (int s = 0; s < 4; ++s)
#pragma unroll
    for (int r = 0; r < 4; ++r) runsum[s][r] = 0.0f;

#pragma unroll
  for (int jt = 0; jt < 4; ++jt) {
    const int jc = colbase + jt * 16;    // col = jc + c
    float colv = 0.0f;
#pragma unroll
    for (int s = 0; s < 4; ++s) {
      floatx4 acc = {0.0f, 0.0f, 0.0f, 0.0f};
#pragma unroll
      for (int kk = 0; kk < 4; ++kk)
        acc = __builtin_amdgcn_mfma_f32_16x16x32_bf16(afrag[s][kk],
                                                      bfrag[jt][kk], acc,
                                                      0, 0, 0);
      const int rb = rowbase + s * 16;   // row = rb + q*4 + r
      if (!isdiag) {                     // off-diagonal block: row+col sums
#pragma unroll
        for (int r = 0; r < 4; ++r) {
          float e = EXP2(acc[r]);
          runsum[s][r] += e;
          colv += e;
        }
      } else if (jc == rb) {             // diagonal 16x16 tile (wave-uniform)
#pragma unroll
        for (int r = 0; r < 4; ++r) {
          float e = EXP2(acc[r]);
          runsum[s][r] += (q * 4 + r == c) ? 0.0f : e;
        }
      } else {                           // diag block, off-diag tile
#pragma unroll
        for (int r = 0; r < 4; ++r) runsum[s][r] += EXP2(acc[r]);
      }
    }

    if (!isdiag) {
      // col sums over this wave's 64 rows: combine the 4 q-groups
      colv += __shfl_xor(colv, 16, 64);
      colv += __shfl_xor(colv, 32, 64);
      if (lane < 16)
        colacc[w][jt * 16 + lane] = colv;   // each col exactly once per wave
    }
  }

  // row partials: reduce across the 16 c-lanes (same q) -> LDS
#pragma unroll
  for (int s = 0; s < 4; ++s)
#pragma unroll
    for (int r = 0; r < 4; ++r) {
      float v = runsum[s][r];
      v += __shfl_xor(v, 1, 64);
      v += __shfl_xor(v, 2, 64);
      v += __shfl_xor(v, 4, 64);
      v += __shfl_xor(v, 8, 64);
      runsum[s][r] = v;
    }
  if (c == 0) {
#pragma unroll
    for (int s = 0; s < 4; ++s)
#pragma unroll
      for (int r = 0; r < 4; ++r)
        rowacc[w][s * 16 + q * 4 + r] = runsum[s][r];
  }

  __syncthreads();
  // combine the two waves sharing each row half / col half, store per block
  float* sblk = scratch + (size_t)blockIdx.x * 256;
  if (t < TILE) {
    const int h = t >> 6, o = t & 63;
    // rows: rowhalf h covered by waves 2h (colhalf 0) and 2h+1 (colhalf 1)
    sblk[t] = rowacc[2 * h][o] + rowacc[2 * h + 1][o];
    // cols: colhalf h covered by waves h (rowhalf 0) and h+2 (rowhalf 1)
    if (!isdiag)
      sblk[128 + t] = colacc[h][o] + colacc[h + 2][o];
  }
}

// ------------------- kernel 3: gather partials, log-reduce -----------------
// grid 64 x 256. Block I handles rows [128I, 128I+128).
// rowsum_i = sum_{J=I..63} scratch[id(I,J)][o] + sum_{I'<I} scratch[id(I',I)][128+o]
// id(I,J) = I*64 - I(I-1)/2 + (J-I);  id(I'+1,I) - id(I',I) = 63 - I'.
// Threads 0..127 gather the row-partial loop, 128..255 the col-partial loop.
__global__ __launch_bounds__(256) void ntx_redu(
    const float* __restrict__ scratch, float* __restrict__ lpart)
{
  __shared__ float sbuf[128];
  __shared__ float red[2];

  const int I = (int)blockIdx.x;
  const int o = (int)threadIdx.x & 127;
  const int half = (int)threadIdx.x >> 7;

  float S = 0.0f;
  if (half == 0) {
    int id = I * TILES - (I * (I - 1)) / 2;      // id(I, I)
#pragma unroll 8
    for (int Jt = I; Jt < TILES; ++Jt, ++id)
      S += scratch[(size_t)id * 256 + o];
  } else {
    int idc = I;                                  // id(0, I)
#pragma unroll 8
    for (int Ip = 0; Ip < I; ++Ip) {
      S += scratch[(size_t)idc * 256 + 128 + o];
      idc += TILES - 1 - Ip;
    }
  }
  if (half) sbuf[o] = S;
  __syncthreads();
  if (!half) {
    float v = __logf(S + sbuf[o]);
#pragma unroll
    for (int m = 1; m <= 32; m <<= 1) v += __shfl_xor(v, m, 64);
    if ((o & 63) == 0) red[o >> 6] = v;
  }
  __syncthreads();
  if (threadIdx.x == 0) lpart[I] = red[0] + red[1];
}

// --------------------------- kernel 4: finalize ----------------------------
__global__ __launch_bounds__(256) void ntx_final(
    const float* __restrict__ lpart, const float* __restrict__ pos,
    float* __restrict__ out)
{
  const int t = threadIdx.x;
  float acc = (t < TILES) ? lpart[t] : 0.0f;
  for (int r = t; r < NHALF; r += 256) acc -= 2.0f * pos[r];
#pragma unroll
  for (int m = 1; m <= 32; m <<= 1) acc += __shfl_xor(acc, m, 64);
  __shared__ float red[4];
  if ((t & 63) == 0) red[t >> 6] = acc;
  __syncthreads();
  if (t == 0) out[0] = (red[0] + red[1] + red[2] + red[3]) / (float)TOTAL;
}

// ---------------------------------------------------------------------------
extern "C" void kernel_launch(void* const* d_in, const int* in_sizes, int n_in,
                              void* d_out, int out_size, void* d_ws,
                              size_t ws_size, hipStream_t stream) {
  const float* zi = (const float*)d_in[0];
  const float* zj = (const float*)d_in[1];
  float* out = (float*)d_out;

  char* ws = (char*)d_ws;
  uint16_t* zn      = (uint16_t*)ws;                          // 2 MiB bf16
  float*    scratch = (float*)(ws + (size_t)TOTAL * DK * 2);  // 2.13 MB
  float*    lpart   = (float*)(ws + (size_t)TOTAL * DK * 2
                               + (size_t)NBLK * 256 * 4);     // 256 B
  float*    pos     = (float*)(ws + (size_t)TOTAL * DK * 2
                               + (size_t)NBLK * 256 * 4 + 256);  // 16 KB

  ntx_norm<<<dim3(NHALF / 4), dim3(256), 0, stream>>>(zi, zj, (uint32_t*)zn,
                                                      pos);
  ntx_gemm<<<dim3(NBLK), dim3(256), 0, stream>>>(zn, scratch);
  ntx_redu<<<dim3(TILES), dim3(256), 0, stream>>>(scratch, lpart);
  ntx_final<<<dim3(1), dim3(256), 0, stream>>>(lpart, pos, out);
}